// Round 9
// baseline (111.630 us; speedup 1.0000x reference)
//
#include <hip/hip_runtime.h>

typedef __attribute__((ext_vector_type(8))) short short8;
typedef __attribute__((ext_vector_type(4))) float f32x4;
typedef __attribute__((ext_vector_type(4))) unsigned int uint4v;

#define P_PTS   1024
#define NN      32
#define NA      60
#define KS      24
#define CIN     32
#define COUT    64
#define AC      12          // anchors per chunk
#define NCH     5           // 60 / 12
#define SA      968         // nf LDS anchor stride (shorts): 24*40 + 8 pad
// gf interleaved layout: short addr = a*1152 + n2*72 + c*2 + parity
//   (dword addr = a*576 + n2*36 + c ; dword = {bf16(n=2*n2), bf16(n=2*n2+1)})
#define GF_SHORTS (AC*16*72)   // 13824 shorts = 27648 B  (>= nf 11616 shorts)

union frag_u { uint4v u; short8 s; };

// full RNE float->bf16
__device__ __forceinline__ unsigned short f2bf(float f) {
  unsigned int u = __float_as_uint(f);
  u += 0x7FFFu + ((u >> 16) & 1u);
  return (unsigned short)(u >> 16);
}
// fast pack: two floats -> bf16x2 (round-half-up)
__device__ __forceinline__ unsigned int bfpair(float a, float b) {
  unsigned int ua = __float_as_uint(a) + 0x8000u;
  unsigned int ub = __float_as_uint(b) + 0x8000u;
  return __builtin_amdgcn_perm(ub, ua, 0x07060302u);  // {hi16(b), hi16(a)}
}
// interleave low/high shorts of two dwords: lo = {u.s0, v.s0}, hi = {u.s1, v.s1}
__device__ __forceinline__ void ilv(unsigned int u, unsigned int v,
                                    unsigned int& lo, unsigned int& hi) {
  lo = __builtin_amdgcn_perm(v, u, 0x05040100u);
  hi = __builtin_amdgcn_perm(v, u, 0x07060302u);
}

// w = relu(1 - d2/0.16) = max(0, (1-6.25|rk|^2) - 6.25|rel|^2 + 12.5<rk,rel>)
__device__ __forceinline__ float wcalc(const float4 rk, const float4 rl) {
  return fmaxf(0.0f, fmaf(rk.x, rl.x, fmaf(rk.y, rl.y, fmaf(rk.z, rl.z, rk.w + rl.w))));
}

// ---------------------------------------------------------------------------
// Fused setup kernel — strictly disjoint block roles (byte-identical to R8):
//   blocks    0..255  : ball query (4 query points each, one per wave)
//   blocks 256..1279  : transpose feats [c][p][a] fp32 -> ft [p][a][c] bf16
//   blocks 1280..1303 : W -> bf16 in MFMA-frag streaming order
//   blocks 1304..1309 : rotated kernel points rk4
// ---------------------------------------------------------------------------
#define SETUP_BLOCKS 1310

__global__ __launch_bounds__(256) void setup_kernel(
    const float* __restrict__ xyz, const float* __restrict__ feats,
    const float* __restrict__ Wm, const float* __restrict__ anchors,
    const float* __restrict__ kernels, int* __restrict__ ws_idx,
    unsigned short* __restrict__ ws_ft, unsigned short* __restrict__ ws_wbf,
    float4* __restrict__ ws_rk4)
{
  const int b   = blockIdx.x;
  const int tid = threadIdx.x;

  __shared__ float sx[P_PTS], sy[P_PTS], sz[P_PTS], sq[P_PTS];
  __shared__ int s_loc[4][NN];
  __shared__ unsigned short s_t[CIN*NA];   // [c][a]

  if (b < 256) {
    // ---- ball query, one query per wave ----
    for (int i = tid; i < P_PTS; i += 256) {
      float x = xyz[i], y = xyz[P_PTS + i], z = xyz[2*P_PTS + i];
      sx[i] = x; sy[i] = y; sz[i] = z;
      sq[i] = x*x + y*y + z*z;
    }
    __syncthreads();
    const int wave = tid >> 6, lane = tid & 63;
    const int q = b*4 + wave;
    const float xq = sx[q], yq = sy[q], zq = sz[q], sqq = sq[q];
    int cnt = 0;
    for (int jb = 0; jb < P_PTS; jb += 64) {
      const int j = jb + lane;
      const float d2 = sqq + sq[j] - 2.0f*(xq*sx[j] + yq*sy[j] + zq*sz[j]);
      const bool pred = d2 < 1.0f;
      const unsigned long long mask = __ballot(pred);
      if (pred) {
        const int slot = cnt + __popcll(mask & ((1ull << lane) - 1ull));
        if (slot < NN) s_loc[wave][slot] = j;
      }
      cnt += (int)__popcll(mask);
      if (cnt >= NN) break;
    }
    __syncthreads();
    const int cntc = cnt < NN ? cnt : NN;
    if (lane >= cntc && lane < NN) s_loc[wave][lane] = s_loc[wave][0];
    __syncthreads();
    if (lane < NN) ws_idx[q*NN + lane] = s_loc[wave][lane];
  } else if (b < 1280) {
    // ---- transpose for p = b - 256 ----
    const int p = b - 256;
    for (int e = tid; e < CIN*NA; e += 256) {
      const int c = e / NA, a = e - c*NA;
      s_t[e] = f2bf(feats[c*(P_PTS*NA) + p*NA + a]);
    }
    __syncthreads();
    unsigned int* out32 = (unsigned int*)(ws_ft + p*(CIN*NA));
    for (int e = tid; e < (CIN*NA)/2; e += 256) {
      const int a = e >> 4, cu = e & 15;
      const unsigned int lo = s_t[(2*cu    )*NA + a];
      const unsigned int hi = s_t[(2*cu + 1)*NA + a];
      out32[a*16 + cu] = lo | (hi << 16);
    }
  } else if (b < 1304) {
    // ---- W -> bf16, MFMA-frag streaming order:
    //      Wf[(((w*24)+s)*64 + lane)*8 + j] = W[o=w*16+lq][c=quad*8+j][k=s]
    const int t = (b - 1280)*256 + tid;      // < 6144
    const int w = t / 1536;
    const int r = t - w*1536;
    const int s = r >> 6;
    const int lane = r & 63;
    const int quad = lane >> 4, lq = lane & 15;
    const int o = w*16 + lq;
    unsigned short h[8];
    #pragma unroll
    for (int j = 0; j < 8; ++j)
      h[j] = f2bf(Wm[o*(CIN*KS) + (quad*8 + j)*KS + s]);
    *(uint4*)(ws_wbf + (size_t)t*8) = *(const uint4*)h;
  } else {
    // ---- rk4 ----
    const int u = (b - 1304)*256 + tid;
    if (u < NA*KS) {
      const int a = u / KS, k = u - a*KS;
      const float rx = anchors[a*9+0]*kernels[k*3+0] + anchors[a*9+1]*kernels[k*3+1] + anchors[a*9+2]*kernels[k*3+2];
      const float ry = anchors[a*9+3]*kernels[k*3+0] + anchors[a*9+4]*kernels[k*3+1] + anchors[a*9+5]*kernels[k*3+2];
      const float rz = anchors[a*9+6]*kernels[k*3+0] + anchors[a*9+7]*kernels[k*3+1] + anchors[a*9+8]*kernels[k*3+2];
      ws_rk4[u] = make_float4(12.5f*rx, 12.5f*ry, 12.5f*rz,
                              1.0f - 6.25f*(rx*rx + ry*ry + rz*rz));
    }
  }
}

// ---------------------------------------------------------------------------
// Main fused kernel, per-point version. Block = point p; loops 5 anchor
// chunks internally. Per-point init hoisted; next chunk's gf gather
// prefetched into registers during contraction 2 of the current chunk.
// Phase math identical to R8's passing kernel.
// ---------------------------------------------------------------------------
__global__ __launch_bounds__(256, 4) void conv_mfma(
    const float* __restrict__ xyz, const unsigned short* __restrict__ ft,
    const unsigned short* __restrict__ Wf, const int* __restrict__ g_idx,
    const float4* __restrict__ g_rk4, float* __restrict__ out)
{
  const int p    = blockIdx.x;
  const int tid  = threadIdx.x;
  const int wave = tid >> 6;
  const int lane = tid & 63;
  const int quad = lane >> 4;
  const int lq   = lane & 15;

  __shared__ __align__(16) unsigned short s_buf[GF_SHORTS];  // 27648 B, aliased by nf
  __shared__ __align__(16) float4 s_rel4[NN];   // (rx,ry,rz,-6.25*|r|^2)
  __shared__ __align__(16) float4 s_rk4[AC*KS];

  // ---- per-point init (once) ----
  if (tid < NN) {
    const int j = g_idx[p*NN + tid];
    const float rx = xyz[j]           - xyz[p];
    const float ry = xyz[P_PTS + j]   - xyz[P_PTS + p];
    const float rz = xyz[2*P_PTS + j] - xyz[2*P_PTS + p];
    s_rel4[tid] = make_float4(rx, ry, rz, -6.25f*(rx*rx + ry*ry + rz*rz));
  }
  // staging coords (fixed across chunks); indices straight from global
  const int np = (tid >> 2) & 15;
  const int ce = tid & 3;
  const int i0 = g_idx[p*NN + 2*np];
  const int i1 = g_idx[p*NN + 2*np + 1];
  const unsigned short* ft0 = ft + (size_t)i0*(CIN*NA) + ce*8;
  const unsigned short* ft1 = ft + (size_t)i1*(CIN*NA) + ce*8;

  // prologue: chunk-0 gf gather into registers
  uint4 pu[3], pv[3];
  #pragma unroll
  for (int i = 0; i < 3; ++i) {
    const int ag = i*4 + wave;          // global anchor, chunk 0
    pu[i] = *(const uint4*)(ft0 + ag*CIN);
    pv[i] = *(const uint4*)(ft1 + ag*CIN);
  }

  const unsigned int* bufd = (const unsigned int*)s_buf;
  const unsigned short* wptr = Wf + (size_t)wave*(24*512) + lane*8;

  for (int ch = 0; ch < NCH; ++ch) {
    const int a0 = ch * AC;

    // ---- rk4 for this chunk + store staged gf regs ----
    for (int e = tid; e < AC*KS; e += 256) s_rk4[e] = g_rk4[a0*KS + e];
    #pragma unroll
    for (int i = 0; i < 3; ++i) {
      const int a = i*4 + wave;         // local anchor
      unsigned short* dst = &s_buf[a*1152 + np*72 + ce*16];
      uint4v w0, w1;
      unsigned int d0, d1;
      ilv(pu[i].x, pv[i].x, d0, d1); w0[0] = d0; w0[1] = d1;
      ilv(pu[i].y, pv[i].y, d0, d1); w0[2] = d0; w0[3] = d1;
      ilv(pu[i].z, pv[i].z, d0, d1); w1[0] = d0; w1[1] = d1;
      ilv(pu[i].w, pv[i].w, d0, d1); w1[2] = d0; w1[3] = d1;
      *(uint4v*)(dst)     = w0;
      *(uint4v*)(dst + 8) = w1;
    }
    __syncthreads();                                   // B1

    // ---- contraction 1: per wave, local anchors wave*3 + {0,1,2} ----
    f32x4 acc1[3][2][2] = {};
    #pragma unroll
    for (int t = 0; t < 3; ++t) {
      const int a = wave*3 + t;
      const int based = a*576 + quad*144 + lq;   // dword addr; rows n2 stride 36
      frag_u af0, af1;
      #pragma unroll
      for (int i = 0; i < 4; ++i) {
        af0.u[i] = bufd[based + 36*i];        // c = lq
        af1.u[i] = bufd[based + 36*i + 16];   // c = 16+lq
      }
      const int k1 = (lq < 8) ? (16 + lq) : 23;     // clamped; cols>=24 discarded
      const float4 rk0 = s_rk4[a*KS + lq];
      const float4 rk1 = s_rk4[a*KS + k1];
      frag_u b0, b1;
      #pragma unroll
      for (int i = 0; i < 4; ++i) {
        const float4 rA = s_rel4[quad*8 + 2*i];
        const float4 rB = s_rel4[quad*8 + 2*i + 1];
        b0.u[i] = bfpair(wcalc(rk0, rA), wcalc(rk0, rB));
        b1.u[i] = bfpair(wcalc(rk1, rA), wcalc(rk1, rB));
      }
      acc1[t][0][0] = __builtin_amdgcn_mfma_f32_16x16x32_bf16(af0.s, b0.s, acc1[t][0][0], 0, 0, 0);
      acc1[t][0][1] = __builtin_amdgcn_mfma_f32_16x16x32_bf16(af0.s, b1.s, acc1[t][0][1], 0, 0, 0);
      acc1[t][1][0] = __builtin_amdgcn_mfma_f32_16x16x32_bf16(af1.s, b0.s, acc1[t][1][0], 0, 0, 0);
      acc1[t][1][1] = __builtin_amdgcn_mfma_f32_16x16x32_bf16(af1.s, b1.s, acc1[t][1][1], 0, 0, 0);
    }
    __syncthreads();                                   // B2 (gf reads done)

    // ---- nf -> LDS bf16 [a][k*40 + c] (aliases gf region) ----
    #pragma unroll
    for (int t = 0; t < 3; ++t) {
      const int a = wave*3 + t;
      unsigned short* row = &s_buf[a*SA];
      uint2 pk;
      pk.x = bfpair(acc1[t][0][0][0], acc1[t][0][0][1]);
      pk.y = bfpair(acc1[t][0][0][2], acc1[t][0][0][3]);
      *(uint2*)&row[lq*40 + quad*4] = pk;                    // mt0, k=lq
      pk.x = bfpair(acc1[t][1][0][0], acc1[t][1][0][1]);
      pk.y = bfpair(acc1[t][1][0][2], acc1[t][1][0][3]);
      *(uint2*)&row[lq*40 + 16 + quad*4] = pk;               // mt1, k=lq
      if (lq < 8) {
        pk.x = bfpair(acc1[t][0][1][0], acc1[t][0][1][1]);
        pk.y = bfpair(acc1[t][0][1][2], acc1[t][0][1][3]);
        *(uint2*)&row[(16+lq)*40 + quad*4] = pk;             // mt0, k=16+lq
        pk.x = bfpair(acc1[t][1][1][0], acc1[t][1][1][1]);
        pk.y = bfpair(acc1[t][1][1][2], acc1[t][1][1][3]);
        *(uint2*)&row[(16+lq)*40 + 16 + quad*4] = pk;        // mt1, k=16+lq
      }
    }
    __syncthreads();                                   // B3 (nf visible)

    // ---- prefetch next chunk's gf gather (hidden behind c2) ----
    if (ch + 1 < NCH) {
      #pragma unroll
      for (int i = 0; i < 3; ++i) {
        const int ag = (ch + 1)*AC + i*4 + wave;
        pu[i] = *(const uint4*)(ft0 + ag*CIN);
        pv[i] = *(const uint4*)(ft1 + ag*CIN);
      }
    }

    // ---- contraction 2: out[o=64][ac=12] = W[64 x 768] * nf[768 x ac] ----
    const int acl = (lq < AC) ? lq : (AC - 1);    // clamp; cols 12..15 discarded
    const unsigned short* nptr = &s_buf[acl*SA + quad*8];
    f32x4 accA = {0.f,0.f,0.f,0.f}, accB = {0.f,0.f,0.f,0.f};
    #pragma unroll 4
    for (int s = 0; s < 24; s += 2) {
      const short8 aw0 = *(const short8*)(wptr + s*512);
      const short8 bn0 = *(const short8*)(nptr + s*40);
      const short8 aw1 = *(const short8*)(wptr + s*512 + 512);
      const short8 bn1 = *(const short8*)(nptr + s*40 + 40);
      accA = __builtin_amdgcn_mfma_f32_16x16x32_bf16(aw0, bn0, accA, 0, 0, 0);
      accB = __builtin_amdgcn_mfma_f32_16x16x32_bf16(aw1, bn1, accB, 0, 0, 0);
    }

    if (lq < AC) {
      const int ob = wave*16 + quad*4;
      #pragma unroll
      for (int r = 0; r < 4; ++r)
        out[(size_t)(ob + r)*(P_PTS*NA) + p*NA + a0 + lq] = accA[r] + accB[r];
    }
    __syncthreads();                                   // B4 (nf reads done; gf reuse safe)
  }
}

// ---------------------------------------------------------------------------
extern "C" void kernel_launch(void* const* d_in, const int* in_sizes, int n_in,
                              void* d_out, int out_size, void* d_ws, size_t ws_size,
                              hipStream_t stream) {
  const float* xyz     = (const float*)d_in[0];   // [1,3,1024]
  const float* feats   = (const float*)d_in[1];   // [1,32,1024,60]
  const float* Wm      = (const float*)d_in[2];   // [64,768]
  const float* anchors = (const float*)d_in[3];   // [60,3,3]
  const float* kernels = (const float*)d_in[4];   // [24,3]
  float* out = (float*)d_out;

  // ws: Wf bf16 (98304 B) | idx (131072 B) | rk4 (23040 B) | ft bf16 (3932160 B)
  unsigned short* ws_wbf = (unsigned short*)d_ws;
  int*    ws_idx = (int*)((char*)d_ws + 98304);
  float4* ws_rk4 = (float4*)((char*)d_ws + 98304 + 131072);
  unsigned short* ws_ft = (unsigned short*)((char*)d_ws + 98304 + 131072 + 23040);

  hipLaunchKernelGGL(setup_kernel, dim3(SETUP_BLOCKS), dim3(256), 0, stream,
                     xyz, feats, Wm, anchors, kernels, ws_idx, ws_ft, ws_wbf, ws_rk4);
  hipLaunchKernelGGL(conv_mfma, dim3(P_PTS), dim3(256), 0, stream,
                     xyz, ws_ft, ws_wbf, ws_idx, ws_rk4, out);
}

// Round 10
// 107.049 us; speedup vs baseline: 1.0428x; 1.0428x over previous
//
#include <hip/hip_runtime.h>

typedef __attribute__((ext_vector_type(8))) short short8;
typedef __attribute__((ext_vector_type(4))) float f32x4;
typedef __attribute__((ext_vector_type(4))) unsigned int uint4v;

#define P_PTS   1024
#define NN      32
#define NA      60
#define KS      24
#define CIN     32
#define COUT    64
#define SA      968         // nf LDS anchor stride (shorts): 24*40 + 8 pad
// gf interleaved layout: short addr = a*1152 + n2*72 + c*2 + parity
//   (dword addr = a*576 + n2*36 + c ; dword = {bf16(n=2*n2), bf16(n=2*n2+1)})
#define GF_SHORTS (16*1152)   // 18432 shorts = 36864 B (>= nf 16*968 shorts)

union frag_u { uint4v u; short8 s; };

// full RNE float->bf16
__device__ __forceinline__ unsigned short f2bf(float f) {
  unsigned int u = __float_as_uint(f);
  u += 0x7FFFu + ((u >> 16) & 1u);
  return (unsigned short)(u >> 16);
}
// fast pack: two floats -> bf16x2 (round-half-up)
__device__ __forceinline__ unsigned int bfpair(float a, float b) {
  unsigned int ua = __float_as_uint(a) + 0x8000u;
  unsigned int ub = __float_as_uint(b) + 0x8000u;
  return __builtin_amdgcn_perm(ub, ua, 0x07060302u);  // {hi16(b), hi16(a)}
}
// interleave low/high shorts of two dwords: lo = {u.s0, v.s0}, hi = {u.s1, v.s1}
__device__ __forceinline__ void ilv(unsigned int u, unsigned int v,
                                    unsigned int& lo, unsigned int& hi) {
  lo = __builtin_amdgcn_perm(v, u, 0x05040100u);
  hi = __builtin_amdgcn_perm(v, u, 0x07060302u);
}

// w = relu(1 - d2/0.16) = max(0, (1-6.25|rk|^2) - 6.25|rel|^2 + 12.5<rk,rel>)
__device__ __forceinline__ float wcalc(const float4 rk, const float4 rl) {
  return fmaxf(0.0f, fmaf(rk.x, rl.x, fmaf(rk.y, rl.y, fmaf(rk.z, rl.z, rk.w + rl.w))));
}

// ---------------------------------------------------------------------------
// Fused setup kernel — strictly disjoint block roles (byte-identical to R8):
//   blocks    0..255  : ball query (4 query points each, one per wave)
//   blocks 256..1279  : transpose feats [c][p][a] fp32 -> ft [p][a][c] bf16
//   blocks 1280..1303 : W -> bf16 in MFMA-frag streaming order
//   blocks 1304..1309 : rotated kernel points rk4
// ---------------------------------------------------------------------------
#define SETUP_BLOCKS 1310

__global__ __launch_bounds__(256) void setup_kernel(
    const float* __restrict__ xyz, const float* __restrict__ feats,
    const float* __restrict__ Wm, const float* __restrict__ anchors,
    const float* __restrict__ kernels, int* __restrict__ ws_idx,
    unsigned short* __restrict__ ws_ft, unsigned short* __restrict__ ws_wbf,
    float4* __restrict__ ws_rk4)
{
  const int b   = blockIdx.x;
  const int tid = threadIdx.x;

  __shared__ float sx[P_PTS], sy[P_PTS], sz[P_PTS], sq[P_PTS];
  __shared__ int s_loc[4][NN];
  __shared__ unsigned short s_t[CIN*NA];   // [c][a]

  if (b < 256) {
    // ---- ball query, one query per wave ----
    for (int i = tid; i < P_PTS; i += 256) {
      float x = xyz[i], y = xyz[P_PTS + i], z = xyz[2*P_PTS + i];
      sx[i] = x; sy[i] = y; sz[i] = z;
      sq[i] = x*x + y*y + z*z;
    }
    __syncthreads();
    const int wave = tid >> 6, lane = tid & 63;
    const int q = b*4 + wave;
    const float xq = sx[q], yq = sy[q], zq = sz[q], sqq = sq[q];
    int cnt = 0;
    for (int jb = 0; jb < P_PTS; jb += 64) {
      const int j = jb + lane;
      const float d2 = sqq + sq[j] - 2.0f*(xq*sx[j] + yq*sy[j] + zq*sz[j]);
      const bool pred = d2 < 1.0f;
      const unsigned long long mask = __ballot(pred);
      if (pred) {
        const int slot = cnt + __popcll(mask & ((1ull << lane) - 1ull));
        if (slot < NN) s_loc[wave][slot] = j;
      }
      cnt += (int)__popcll(mask);
      if (cnt >= NN) break;
    }
    __syncthreads();
    const int cntc = cnt < NN ? cnt : NN;
    if (lane >= cntc && lane < NN) s_loc[wave][lane] = s_loc[wave][0];
    __syncthreads();
    if (lane < NN) ws_idx[q*NN + lane] = s_loc[wave][lane];
  } else if (b < 1280) {
    // ---- transpose for p = b - 256 ----
    const int p = b - 256;
    for (int e = tid; e < CIN*NA; e += 256) {
      const int c = e / NA, a = e - c*NA;
      s_t[e] = f2bf(feats[c*(P_PTS*NA) + p*NA + a]);
    }
    __syncthreads();
    unsigned int* out32 = (unsigned int*)(ws_ft + p*(CIN*NA));
    for (int e = tid; e < (CIN*NA)/2; e += 256) {
      const int a = e >> 4, cu = e & 15;
      const unsigned int lo = s_t[(2*cu    )*NA + a];
      const unsigned int hi = s_t[(2*cu + 1)*NA + a];
      out32[a*16 + cu] = lo | (hi << 16);
    }
  } else if (b < 1304) {
    // ---- W -> bf16, MFMA-frag streaming order:
    //      Wf[(((w*24)+s)*64 + lane)*8 + j] = W[o=w*16+lq][c=quad*8+j][k=s]
    const int t = (b - 1280)*256 + tid;      // < 6144
    const int w = t / 1536;
    const int r = t - w*1536;
    const int s = r >> 6;
    const int lane = r & 63;
    const int quad = lane >> 4, lq = lane & 15;
    const int o = w*16 + lq;
    unsigned short h[8];
    #pragma unroll
    for (int j = 0; j < 8; ++j)
      h[j] = f2bf(Wm[o*(CIN*KS) + (quad*8 + j)*KS + s]);
    *(uint4*)(ws_wbf + (size_t)t*8) = *(const uint4*)h;
  } else {
    // ---- rk4 ----
    const int u = (b - 1304)*256 + tid;
    if (u < NA*KS) {
      const int a = u / KS, k = u - a*KS;
      const float rx = anchors[a*9+0]*kernels[k*3+0] + anchors[a*9+1]*kernels[k*3+1] + anchors[a*9+2]*kernels[k*3+2];
      const float ry = anchors[a*9+3]*kernels[k*3+0] + anchors[a*9+4]*kernels[k*3+1] + anchors[a*9+5]*kernels[k*3+2];
      const float rz = anchors[a*9+6]*kernels[k*3+0] + anchors[a*9+7]*kernels[k*3+1] + anchors[a*9+8]*kernels[k*3+2];
      ws_rk4[u] = make_float4(12.5f*rx, 12.5f*ry, 12.5f*rz,
                              1.0f - 6.25f*(rx*rx + ry*ry + rz*rz));
    }
  }
}

// ---------------------------------------------------------------------------
// One anchor-chunk of the conv: NAW anchors per wave (chunk = 4*NAW anchors),
// NAWN = next chunk's anchors-per-wave (0 = last). rk read direct from global
// (L1/L2-resident); nf aliases gf region between barriers.
// ---------------------------------------------------------------------------
template<int NAW, int NAWN>
__device__ __forceinline__ void chunk_body(
    const int a0, const int wave, const int quad, const int lq,
    const int np, const int ce,
    const unsigned short* __restrict__ ft0, const unsigned short* __restrict__ ft1,
    unsigned short* __restrict__ s_buf, const float4* __restrict__ s_rel4,
    const float4* __restrict__ g_rk4, const unsigned short* __restrict__ wptr,
    float* __restrict__ out, const int p, uint4* pu, uint4* pv)
{
  constexpr int NACH = NAW * 4;

  // ---- store staged gf regs (interleaved pair layout) ----
  #pragma unroll
  for (int i = 0; i < NAW; ++i) {
    const int a = i*4 + wave;
    unsigned short* dst = &s_buf[a*1152 + np*72 + ce*16];
    uint4v w0, w1;
    unsigned int d0, d1;
    ilv(pu[i].x, pv[i].x, d0, d1); w0[0] = d0; w0[1] = d1;
    ilv(pu[i].y, pv[i].y, d0, d1); w0[2] = d0; w0[3] = d1;
    ilv(pu[i].z, pv[i].z, d0, d1); w1[0] = d0; w1[1] = d1;
    ilv(pu[i].w, pv[i].w, d0, d1); w1[2] = d0; w1[3] = d1;
    *(uint4v*)(dst)     = w0;
    *(uint4v*)(dst + 8) = w1;
  }
  __syncthreads();                                   // B1

  // ---- contraction 1: per wave, local anchors wave*NAW + t ----
  const unsigned int* bufd = (const unsigned int*)s_buf;
  f32x4 acc1[NAW][2][2] = {};
  #pragma unroll
  for (int t = 0; t < NAW; ++t) {
    const int a = wave*NAW + t;
    const int based = a*576 + quad*144 + lq;   // dword addr; rows n2 stride 36
    frag_u af0, af1;
    #pragma unroll
    for (int i = 0; i < 4; ++i) {
      af0.u[i] = bufd[based + 36*i];        // c = lq
      af1.u[i] = bufd[based + 36*i + 16];   // c = 16+lq
    }
    const int k1 = (lq < 8) ? (16 + lq) : 23;     // clamped; cols>=24 discarded
    const float4 rk0 = g_rk4[(a0 + a)*KS + lq];
    const float4 rk1 = g_rk4[(a0 + a)*KS + k1];
    frag_u b0, b1;
    #pragma unroll
    for (int i = 0; i < 4; ++i) {
      const float4 rA = s_rel4[quad*8 + 2*i];
      const float4 rB = s_rel4[quad*8 + 2*i + 1];
      b0.u[i] = bfpair(wcalc(rk0, rA), wcalc(rk0, rB));
      b1.u[i] = bfpair(wcalc(rk1, rA), wcalc(rk1, rB));
    }
    acc1[t][0][0] = __builtin_amdgcn_mfma_f32_16x16x32_bf16(af0.s, b0.s, acc1[t][0][0], 0, 0, 0);
    acc1[t][0][1] = __builtin_amdgcn_mfma_f32_16x16x32_bf16(af0.s, b1.s, acc1[t][0][1], 0, 0, 0);
    acc1[t][1][0] = __builtin_amdgcn_mfma_f32_16x16x32_bf16(af1.s, b0.s, acc1[t][1][0], 0, 0, 0);
    acc1[t][1][1] = __builtin_amdgcn_mfma_f32_16x16x32_bf16(af1.s, b1.s, acc1[t][1][1], 0, 0, 0);
  }
  __syncthreads();                                   // B2 (gf reads done)

  // ---- nf -> LDS bf16 [a][k*40 + c] (aliases gf region) ----
  #pragma unroll
  for (int t = 0; t < NAW; ++t) {
    const int a = wave*NAW + t;
    unsigned short* row = &s_buf[a*SA];
    uint2 pk;
    pk.x = bfpair(acc1[t][0][0][0], acc1[t][0][0][1]);
    pk.y = bfpair(acc1[t][0][0][2], acc1[t][0][0][3]);
    *(uint2*)&row[lq*40 + quad*4] = pk;                    // mt0, k=lq
    pk.x = bfpair(acc1[t][1][0][0], acc1[t][1][0][1]);
    pk.y = bfpair(acc1[t][1][0][2], acc1[t][1][0][3]);
    *(uint2*)&row[lq*40 + 16 + quad*4] = pk;               // mt1, k=lq
    if (lq < 8) {
      pk.x = bfpair(acc1[t][0][1][0], acc1[t][0][1][1]);
      pk.y = bfpair(acc1[t][0][1][2], acc1[t][0][1][3]);
      *(uint2*)&row[(16+lq)*40 + quad*4] = pk;             // mt0, k=16+lq
      pk.x = bfpair(acc1[t][1][1][0], acc1[t][1][1][1]);
      pk.y = bfpair(acc1[t][1][1][2], acc1[t][1][1][3]);
      *(uint2*)&row[(16+lq)*40 + 16 + quad*4] = pk;        // mt1, k=16+lq
    }
  }
  __syncthreads();                                   // B3 (nf visible)

  // ---- prefetch next chunk's gf gather (hidden behind c2) ----
  #pragma unroll
  for (int i = 0; i < NAWN; ++i) {
    const int ag = a0 + NACH + i*4 + wave;
    pu[i] = *(const uint4*)(ft0 + ag*CIN);
    pv[i] = *(const uint4*)(ft1 + ag*CIN);
  }

  // ---- contraction 2: out[o=64][NACH] = W[64 x 768] * nf[768 x NACH] ----
  const int acl = (NACH >= 16) ? lq : ((lq < NACH) ? lq : (NACH - 1));
  const unsigned short* nptr = &s_buf[acl*SA + quad*8];
  f32x4 accA = {0.f,0.f,0.f,0.f}, accB = {0.f,0.f,0.f,0.f};
  #pragma unroll 4
  for (int s = 0; s < 24; s += 2) {
    const short8 aw0 = *(const short8*)(wptr + s*512);
    const short8 bn0 = *(const short8*)(nptr + s*40);
    const short8 aw1 = *(const short8*)(wptr + s*512 + 512);
    const short8 bn1 = *(const short8*)(nptr + s*40 + 40);
    accA = __builtin_amdgcn_mfma_f32_16x16x32_bf16(aw0, bn0, accA, 0, 0, 0);
    accB = __builtin_amdgcn_mfma_f32_16x16x32_bf16(aw1, bn1, accB, 0, 0, 0);
  }

  if (NACH >= 16 || lq < NACH) {
    const int ob = wave*16 + quad*4;
    #pragma unroll
    for (int r = 0; r < 4; ++r)
      out[(size_t)(ob + r)*(P_PTS*NA) + p*NA + a0 + lq] = accA[r] + accB[r];
  }
  __syncthreads();                                   // B4 (nf reads done; gf reuse safe)
}

// ---------------------------------------------------------------------------
// Main fused kernel. Block = point p; anchor chunks 16,16,16,12.
// ---------------------------------------------------------------------------
__global__ __launch_bounds__(256, 4) void conv_mfma(
    const float* __restrict__ xyz, const unsigned short* __restrict__ ft,
    const unsigned short* __restrict__ Wf, const int* __restrict__ g_idx,
    const float4* __restrict__ g_rk4, float* __restrict__ out)
{
  const int p    = blockIdx.x;
  const int tid  = threadIdx.x;
  const int wave = tid >> 6;
  const int lane = tid & 63;
  const int quad = lane >> 4;
  const int lq   = lane & 15;

  __shared__ __align__(16) unsigned short s_buf[GF_SHORTS];  // 36864 B, aliased by nf
  __shared__ __align__(16) float4 s_rel4[NN];   // (rx,ry,rz,-6.25*|r|^2)

  // ---- per-point init (once) ----
  if (tid < NN) {
    const int j = g_idx[p*NN + tid];
    const float rx = xyz[j]           - xyz[p];
    const float ry = xyz[P_PTS + j]   - xyz[P_PTS + p];
    const float rz = xyz[2*P_PTS + j] - xyz[2*P_PTS + p];
    s_rel4[tid] = make_float4(rx, ry, rz, -6.25f*(rx*rx + ry*ry + rz*rz));
  }
  const int np = (tid >> 2) & 15;
  const int ce = tid & 3;
  const int i0 = g_idx[p*NN + 2*np];
  const int i1 = g_idx[p*NN + 2*np + 1];
  const unsigned short* ft0 = ft + (size_t)i0*(CIN*NA) + ce*8;
  const unsigned short* ft1 = ft + (size_t)i1*(CIN*NA) + ce*8;

  // prologue: chunk-0 gf gather into registers
  uint4 pu[4], pv[4];
  #pragma unroll
  for (int i = 0; i < 4; ++i) {
    const int ag = i*4 + wave;
    pu[i] = *(const uint4*)(ft0 + ag*CIN);
    pv[i] = *(const uint4*)(ft1 + ag*CIN);
  }
  const unsigned short* wptr = Wf + (size_t)wave*(24*512) + lane*8;

  chunk_body<4,4>( 0, wave, quad, lq, np, ce, ft0, ft1, s_buf, s_rel4, g_rk4, wptr, out, p, pu, pv);
  chunk_body<4,4>(16, wave, quad, lq, np, ce, ft0, ft1, s_buf, s_rel4, g_rk4, wptr, out, p, pu, pv);
  chunk_body<4,3>(32, wave, quad, lq, np, ce, ft0, ft1, s_buf, s_rel4, g_rk4, wptr, out, p, pu, pv);
  chunk_body<3,0>(48, wave, quad, lq, np, ce, ft0, ft1, s_buf, s_rel4, g_rk4, wptr, out, p, pu, pv);
}

// ---------------------------------------------------------------------------
extern "C" void kernel_launch(void* const* d_in, const int* in_sizes, int n_in,
                              void* d_out, int out_size, void* d_ws, size_t ws_size,
                              hipStream_t stream) {
  const float* xyz     = (const float*)d_in[0];   // [1,3,1024]
  const float* feats   = (const float*)d_in[1];   // [1,32,1024,60]
  const float* Wm      = (const float*)d_in[2];   // [64,768]
  const float* anchors = (const float*)d_in[3];   // [60,3,3]
  const float* kernels = (const float*)d_in[4];   // [24,3]
  float* out = (float*)d_out;

  // ws: Wf bf16 (98304 B) | idx (131072 B) | rk4 (23040 B) | ft bf16 (3932160 B)
  unsigned short* ws_wbf = (unsigned short*)d_ws;
  int*    ws_idx = (int*)((char*)d_ws + 98304);
  float4* ws_rk4 = (float4*)((char*)d_ws + 98304 + 131072);
  unsigned short* ws_ft = (unsigned short*)((char*)d_ws + 98304 + 131072 + 23040);

  hipLaunchKernelGGL(setup_kernel, dim3(SETUP_BLOCKS), dim3(256), 0, stream,
                     xyz, feats, Wm, anchors, kernels, ws_idx, ws_ft, ws_wbf, ws_rk4);
  hipLaunchKernelGGL(conv_mfma, dim3(P_PTS), dim3(256), 0, stream,
                     xyz, ws_ft, ws_wbf, ws_idx, ws_rk4, out);
}